// Round 3
// baseline (102.872 us; speedup 1.0000x reference)
//
#include <hip/hip_runtime.h>
#include <hip/hip_bf16.h>

// Problem constants (B, N, K, P, D, F, H) = (8, 20, 2, 320, 3, 64, 64)
// Inputs: float32 (nbr_idx int32). Output: float32 (reference output dtype).
constexpr int B_ = 8, N_ = 20, K_ = 2, P_ = 320, D_ = 3, F_ = 64, H_ = 64;
constexpr int Q_ = K_ * P_;          // 640 = flattened (K,P) of a node
constexpr float EPS_ = 1e-8f;

// One block per (b, n). 640 threads: thread = one output row (k,p), k = tid/320.
// 320 = 5 full waves -> k is wave-uniform -> LDS q-loop reads are broadcasts.
__global__ __launch_bounds__(Q_) void dnbp_kernel(
    const float* __restrict__ X,      // (B,N,K,P,D)
    const float* __restrict__ W,      // (B,N,K,P)
    const float* __restrict__ feats,  // (B,N,F)
    const float* __restrict__ mu,     // (N,K,D)
    const float* __restrict__ W1,     // (N,F,H)
    const float* __restrict__ Wx,     // (N,D,H)
    const float* __restrict__ b1,     // (N,H)
    const float* __restrict__ W2,     // (N,H)
    const float* __restrict__ bias2,  // (N,)
    const int* __restrict__ nbr,      // (N,2)
    float* __restrict__ out)          // (B,N,K,P) float32
{
    // xn4[k][q] = (xn_x, xn_y, xn_z, cq) with cq = Wnb_q * exp(-2*|xn_q|^2)
    __shared__ float4 xn4[K_][Q_];
    __shared__ float4 wx4[H_];     // (Wx[0][h], Wx[1][h], Wx[2][h], W2[h])
    __shared__ float  hb[H_];      // hf[h] + b1[h]
    __shared__ float  red[2 * 10];
    __shared__ float  sumW[2];     // reciprocal of (sum W_neighbor + EPS)
    __shared__ float  totalS;      // reciprocal of (sum w + EPS)

    const int bn  = blockIdx.x;     // 0..159
    const int b   = bn / N_;
    const int n   = bn - b * N_;
    const int tid = threadIdx.x;    // 0..639
    const int wave = tid >> 6;
    const int lane = tid & 63;

    const int j0 = nbr[n * 2 + 0];
    const int j1 = nbr[n * 2 + 1];

    // ---- gate parameters: hf = feats[b,n] @ W1[n]; pack Wx/W2 (threads 0..63) ----
    if (tid < H_) {
        const int h = tid;
        const float* fp  = feats + ((size_t)b * N_ + n) * F_;
        const float* w1p = W1 + (size_t)n * F_ * H_ + h;
        float acc = 0.f;
        #pragma unroll 8
        for (int f = 0; f < F_; ++f)
            acc = fmaf(fp[f], w1p[(size_t)f * H_], acc);
        hb[h] = acc + b1[n * H_ + h];
        const float* wxp = Wx + (size_t)n * D_ * H_ + h;
        wx4[h] = make_float4(wxp[0], wxp[H_], wxp[2 * H_], W2[n * H_ + h]);
    }

    // ---- stage both neighbors' X (flattened KP=640) + raw weights ----
    const int q = tid;
    float w0, w1;
    {
        const size_t base0 = ((size_t)b * N_ + j0) * Q_ + q;
        const float* xp = X + base0 * D_;
        const float x0 = xp[0], x1 = xp[1], x2 = xp[2];
        const float sq = x0 * x0 + x1 * x1 + x2 * x2;
        w0 = W[base0];
        xn4[0][q] = make_float4(x0, x1, x2, w0 * __expf(-2.f * sq));
    }
    {
        const size_t base1 = ((size_t)b * N_ + j1) * Q_ + q;
        const float* xp = X + base1 * D_;
        const float x0 = xp[0], x1 = xp[1], x2 = xp[2];
        const float sq = x0 * x0 + x1 * x1 + x2 * x2;
        w1 = W[base1];
        xn4[1][q] = make_float4(x0, x1, x2, w1 * __expf(-2.f * sq));
    }

    // ---- block-reduce neighbor weight sums (both neighbors at once) ----
    {
        float v0 = w0, v1 = w1;
        #pragma unroll
        for (int off = 32; off > 0; off >>= 1) {
            v0 += __shfl_down(v0, off, 64);
            v1 += __shfl_down(v1, off, 64);
        }
        if (lane == 0) { red[wave * 2] = v0; red[wave * 2 + 1] = v1; }
        __syncthreads();
        if (tid == 0) {
            float s0 = 0.f, s1 = 0.f;
            #pragma unroll
            for (int wv = 0; wv < 10; ++wv) { s0 += red[wv * 2]; s1 += red[wv * 2 + 1]; }
            sumW[0] = 1.f / (s0 + EPS_);
            sumW[1] = 1.f / (s1 + EPS_);
        }
        __syncthreads();
    }

    // ---- fold normalized weight into cq (each thread touches only its own q) ----
    xn4[0][q].w *= sumW[0];
    xn4[1][q].w *= sumW[1];
    __syncthreads();

    // ---- per-row work ----
    const int k = (tid >= P_) ? 1 : 0;   // wave-uniform (320 = 5 waves)
    const int p = tid - k * P_;
    const size_t rowbase = (((size_t)b * N_ + n) * K_ + k) * P_ + p;
    const float* xp = X + rowbase * D_;
    const float x0 = xp[0], x1 = xp[1], x2 = xp[2];
    const float* mup = mu + (n * K_ + k) * D_;
    const float a0 = x0 - mup[0];
    const float a1 = x1 - mup[1];
    const float a2 = x2 - mup[2];
    const float ra2 = a0 * a0 + a1 * a1 + a2 * a2;

    // gate: u = sigmoid( sum_h relu(hf+b1 + X.Wx)[h] * W2[h] + bias2 )
    float acc = bias2[n];
    #pragma unroll 8
    for (int h = 0; h < H_; ++h) {
        const float4 wv = wx4[h];
        float t = fmaf(x0, wv.x, fmaf(x1, wv.y, fmaf(x2, wv.z, hb[h])));
        t = fmaxf(t, 0.f);
        acc = fmaf(t, wv.w, acc);
    }
    const float u = 1.f / (1.f + __expf(-acc));

    // message: msg = exp(-2|a|^2) * sum_q cq * exp(4 * a.xn_q)
    const float4* __restrict__ xk = xn4[k];
    float m0 = 0.f, m1 = 0.f;
    #pragma unroll 4
    for (int qq = 0; qq < Q_; qq += 2) {
        const float4 f0 = xk[qq];
        const float4 f1 = xk[qq + 1];
        const float d0 = fmaf(a0, f0.x, fmaf(a1, f0.y, a2 * f0.z));
        const float d1 = fmaf(a0, f1.x, fmaf(a1, f1.y, a2 * f1.z));
        m0 = fmaf(f0.w, __expf(4.f * d0), m0);
        m1 = fmaf(f1.w, __expf(4.f * d1), m1);
    }
    const float msg = (m0 + m1) * __expf(-2.f * ra2);
    const float wval = u * msg;

    // ---- normalize over (k,p): block reduction of wval ----
    {
        float v = wval;
        #pragma unroll
        for (int off = 32; off > 0; off >>= 1) v += __shfl_down(v, off, 64);
        if (lane == 0) red[wave] = v;
        __syncthreads();
        if (tid == 0) {
            float s = 0.f;
            #pragma unroll
            for (int wv = 0; wv < 10; ++wv) s += red[wv];
            totalS = 1.f / (s + EPS_);
        }
        __syncthreads();
    }

    out[((size_t)b * N_ + n) * Q_ + tid] = wval * totalS;
}

extern "C" void kernel_launch(void* const* d_in, const int* in_sizes, int n_in,
                              void* d_out, int out_size, void* d_ws, size_t ws_size,
                              hipStream_t stream) {
    const float* X     = (const float*)d_in[0];
    const float* W     = (const float*)d_in[1];
    const float* feats = (const float*)d_in[2];
    const float* mu    = (const float*)d_in[3];
    const float* W1    = (const float*)d_in[4];
    const float* Wx    = (const float*)d_in[5];
    const float* b1    = (const float*)d_in[6];
    const float* W2    = (const float*)d_in[7];
    const float* bias2 = (const float*)d_in[8];
    const int*   nbr   = (const int*)d_in[9];
    float*       out   = (float*)d_out;

    dnbp_kernel<<<B_ * N_, Q_, 0, stream>>>(X, W, feats, mu, W1, Wx, b1, W2,
                                            bias2, nbr, out);
}

// Round 4
// 97.244 us; speedup vs baseline: 1.0579x; 1.0579x over previous
//
#include <hip/hip_runtime.h>
#include <hip/hip_bf16.h>

// Problem constants (B, N, K, P, D, F, H) = (8, 20, 2, 320, 3, 64, 64)
// Inputs: float32 (nbr_idx int32). Output: float32.
constexpr int B_ = 8, N_ = 20, K_ = 2, P_ = 320, D_ = 3, F_ = 64, H_ = 64;
constexpr int Q_ = K_ * P_;          // 640 = flattened (K,P) of a node
constexpr float EPS_ = 1e-8f;
constexpr float LOG2E_ = 1.4426950408889634f;

// One block per (b, n). 640 threads: thread = one output row (k,p), k = tid/320.
// 320 = 5 full waves -> k is wave-uniform -> LDS q-loop reads are broadcasts.
// exp factorization: exp(-d2/(2*sigma^2)) with sigma=0.5 -> exp(-2*d2),
//   exp(-2*d2) = exp(-2|a|^2) * exp(-2|xn|^2) * exp(4*a.xn); all exps done as
//   exp2 with log2e folded into the operands once per row / per staged point.
__global__ __launch_bounds__(Q_) void dnbp_kernel(
    const float* __restrict__ X,      // (B,N,K,P,D)
    const float* __restrict__ W,      // (B,N,K,P)
    const float* __restrict__ feats,  // (B,N,F)
    const float* __restrict__ mu,     // (N,K,D)
    const float* __restrict__ W1,     // (N,F,H)
    const float* __restrict__ Wx,     // (N,D,H)
    const float* __restrict__ b1,     // (N,H)
    const float* __restrict__ W2,     // (N,H)
    const float* __restrict__ bias2,  // (N,)
    const int* __restrict__ nbr,      // (N,2)
    float* __restrict__ out)          // (B,N,K,P) float32
{
    // xn4[k][q] = (xn_x, xn_y, xn_z, cq), cq = Wnb_q/sumW * exp(-2*|xn_q|^2)
    __shared__ float4 xn4[K_][Q_];
    __shared__ float4 wx4[H_];     // (Wx[0][h], Wx[1][h], Wx[2][h], W2[h])
    __shared__ float  hb[H_];      // hf[h] + b1[h]
    __shared__ float  red[2 * 10];
    __shared__ float  sumW[2];     // 1 / (sum W_neighbor + EPS)
    __shared__ float  totalS;      // 1 / (sum w + EPS)

    const int bn  = blockIdx.x;     // 0..159
    const int b   = bn / N_;
    const int n   = bn - b * N_;
    const int tid = threadIdx.x;    // 0..639
    const int wave = tid >> 6;
    const int lane = tid & 63;

    const int j0 = nbr[n * 2 + 0];
    const int j1 = nbr[n * 2 + 1];

    // ---- gate parameters: hf = feats[b,n] @ W1[n]; pack Wx/W2 (threads 0..63) ----
    if (tid < H_) {
        const int h = tid;
        const float* fp  = feats + ((size_t)b * N_ + n) * F_;
        const float* w1p = W1 + (size_t)n * F_ * H_ + h;
        float acc = 0.f;
        #pragma unroll 8
        for (int f = 0; f < F_; ++f)
            acc = fmaf(fp[f], w1p[(size_t)f * H_], acc);
        hb[h] = acc + b1[n * H_ + h];
        const float* wxp = Wx + (size_t)n * D_ * H_ + h;
        wx4[h] = make_float4(wxp[0], wxp[H_], wxp[2 * H_], W2[n * H_ + h]);
    }

    // ---- stage both neighbors' X (flattened KP=640) + raw weights ----
    const int q = tid;
    float w0, w1;
    {
        const size_t base0 = ((size_t)b * N_ + j0) * Q_ + q;
        const float* xp = X + base0 * D_;
        const float x0 = xp[0], x1 = xp[1], x2 = xp[2];
        const float sq = x0 * x0 + x1 * x1 + x2 * x2;
        w0 = W[base0];
        xn4[0][q] = make_float4(x0, x1, x2,
                                w0 * __builtin_amdgcn_exp2f(-2.f * LOG2E_ * sq));
    }
    {
        const size_t base1 = ((size_t)b * N_ + j1) * Q_ + q;
        const float* xp = X + base1 * D_;
        const float x0 = xp[0], x1 = xp[1], x2 = xp[2];
        const float sq = x0 * x0 + x1 * x1 + x2 * x2;
        w1 = W[base1];
        xn4[1][q] = make_float4(x0, x1, x2,
                                w1 * __builtin_amdgcn_exp2f(-2.f * LOG2E_ * sq));
    }

    // ---- block-reduce neighbor weight sums (both neighbors at once) ----
    {
        float v0 = w0, v1 = w1;
        #pragma unroll
        for (int off = 32; off > 0; off >>= 1) {
            v0 += __shfl_down(v0, off, 64);
            v1 += __shfl_down(v1, off, 64);
        }
        if (lane == 0) { red[wave * 2] = v0; red[wave * 2 + 1] = v1; }
        __syncthreads();
        if (tid == 0) {
            float s0 = 0.f, s1 = 0.f;
            #pragma unroll
            for (int wv = 0; wv < 10; ++wv) { s0 += red[wv * 2]; s1 += red[wv * 2 + 1]; }
            sumW[0] = 1.f / (s0 + EPS_);
            sumW[1] = 1.f / (s1 + EPS_);
        }
        __syncthreads();
    }

    // ---- fold normalized weight into cq (each thread touches only its own q) ----
    xn4[0][q].w *= sumW[0];
    xn4[1][q].w *= sumW[1];
    __syncthreads();

    // ---- per-row work ----
    const int k = (tid >= P_) ? 1 : 0;   // wave-uniform (320 = 5 waves)
    const int p = tid - k * P_;
    const size_t rowbase = (((size_t)b * N_ + n) * K_ + k) * P_ + p;
    const float* xp = X + rowbase * D_;
    const float x0 = xp[0], x1 = xp[1], x2 = xp[2];
    const float* mup = mu + (n * K_ + k) * D_;
    const float a0 = x0 - mup[0];
    const float a1 = x1 - mup[1];
    const float a2 = x2 - mup[2];
    const float ra2 = a0 * a0 + a1 * a1 + a2 * a2;
    // prescale so the inner dot directly yields the exp2 argument
    const float s0 = a0 * (4.f * LOG2E_);
    const float s1 = a1 * (4.f * LOG2E_);
    const float s2 = a2 * (4.f * LOG2E_);

    // gate: u = sigmoid( sum_h relu(hf+b1 + X.Wx)[h] * W2[h] + bias2 )
    float acc = bias2[n];
    #pragma unroll 8
    for (int h = 0; h < H_; ++h) {
        const float4 wv = wx4[h];
        float t = fmaf(x0, wv.x, fmaf(x1, wv.y, fmaf(x2, wv.z, hb[h])));
        t = fmaxf(t, 0.f);
        acc = fmaf(t, wv.w, acc);
    }
    const float u = 1.f / (1.f + __expf(-acc));

    // message: msg = exp2(-2*log2e*|a|^2) * sum_q cq * exp2(s . xn_q)
    const float4* __restrict__ xk = xn4[k];
    float m0 = 0.f, m1 = 0.f, m2 = 0.f, m3 = 0.f;
    #pragma unroll 2
    for (int qq = 0; qq < Q_; qq += 4) {
        const float4 f0 = xk[qq];
        const float4 f1 = xk[qq + 1];
        const float4 f2 = xk[qq + 2];
        const float4 f3 = xk[qq + 3];
        const float d0 = fmaf(s0, f0.x, fmaf(s1, f0.y, s2 * f0.z));
        const float d1 = fmaf(s0, f1.x, fmaf(s1, f1.y, s2 * f1.z));
        const float d2 = fmaf(s0, f2.x, fmaf(s1, f2.y, s2 * f2.z));
        const float d3 = fmaf(s0, f3.x, fmaf(s1, f3.y, s2 * f3.z));
        m0 = fmaf(f0.w, __builtin_amdgcn_exp2f(d0), m0);
        m1 = fmaf(f1.w, __builtin_amdgcn_exp2f(d1), m1);
        m2 = fmaf(f2.w, __builtin_amdgcn_exp2f(d2), m2);
        m3 = fmaf(f3.w, __builtin_amdgcn_exp2f(d3), m3);
    }
    const float msg = ((m0 + m1) + (m2 + m3)) *
                      __builtin_amdgcn_exp2f(-2.f * LOG2E_ * ra2);
    const float wval = u * msg;

    // ---- normalize over (k,p): block reduction of wval ----
    {
        float v = wval;
        #pragma unroll
        for (int off = 32; off > 0; off >>= 1) v += __shfl_down(v, off, 64);
        if (lane == 0) red[wave] = v;
        __syncthreads();
        if (tid == 0) {
            float s = 0.f;
            #pragma unroll
            for (int wv = 0; wv < 10; ++wv) s += red[wv];
            totalS = 1.f / (s + EPS_);
        }
        __syncthreads();
    }

    out[((size_t)b * N_ + n) * Q_ + tid] = wval * totalS;
}

extern "C" void kernel_launch(void* const* d_in, const int* in_sizes, int n_in,
                              void* d_out, int out_size, void* d_ws, size_t ws_size,
                              hipStream_t stream) {
    const float* X     = (const float*)d_in[0];
    const float* W     = (const float*)d_in[1];
    const float* feats = (const float*)d_in[2];
    const float* mu    = (const float*)d_in[3];
    const float* W1    = (const float*)d_in[4];
    const float* Wx    = (const float*)d_in[5];
    const float* b1    = (const float*)d_in[6];
    const float* W2    = (const float*)d_in[7];
    const float* bias2 = (const float*)d_in[8];
    const int*   nbr   = (const int*)d_in[9];
    float*       out   = (float*)d_out;

    dnbp_kernel<<<B_ * N_, Q_, 0, stream>>>(X, W, feats, mu, W1, Wx, b1, W2,
                                            bias2, nbr, out);
}